// Round 7
// baseline (174.454 us; speedup 1.0000x reference)
//
#include <hip/hip_runtime.h>
#include <math.h>

#define NWAY 5
#define KSHOT 5
#define PRJ 14
#define DD 64
#define PP 100
#define NQ 1024
#define NS 350
#define NPAIR 70
#define LAMDA 32.0f
#define MARGIN 0.3f
#define PCHUNK 25
#define FGROUPS 32
#define SUBCH 2

// ---- workspace layout (floats), ~29.6 MB ----
#define VPT_OFF   0          // [70][100][64]  = 448000  ([p][d])
#define VPTS_OFF  448000     // [350][6400]    = 2240000 (per-sample normalized, [p][d])
#define B2_OFF    2688000    // [6400][72]     = 460800  (f=d*100+p major, pair-contig)
#define MM_OFF    3148800    // [70][100]      = 7000
#define VNINV_OFF 3155800    // [70] pad 128
#define PSUM_OFF  3155928    // [70][64] = 4480
#define BASE_OFF  3160408    // [5][64]
#define QV_OFF    3160728    // [1024][64] = 65536
#define INVQ_OFF  3226264    // [1024][100] = 102400
#define SIM32_OFF 3328664    // [32][1024][70] = 2293760
#define SIM_OFF   5622424    // [1024][70] = 71680
#define PW_OFF    5694104    // [1024][70] = 71680
#define PQ4_OFF   5765784    // [4][1024][5][64] = 1310720
#define PQ_OFF    7076504    // [1024][5][64] = 327680
#define CLS_OFF   7404184    // [1024]
#define ALN_OFF   7405208    // [1024]

#define PQ_ELEMS (NQ*NWAY*64)
#define SIM_STRIDE (NQ*NPAIR)

__device__ __forceinline__ float redsum64(float x){
  #pragma unroll
  for (int o = 1; o < 64; o <<= 1) x += __shfl_xor(x, o, 64);
  return x;
}

// ---------------- kVa: one block per support sample -> normalized/L2(pos) ----------------
__global__ __launch_bounds__(256) void kVa(const float* __restrict__ feat,
                                           float* __restrict__ vptS){
  __shared__ float lds[64*101];
  __shared__ float inv[100];
  int s = blockIdx.x, t = threadIdx.x;
  const float* fp = feat + (size_t)s * 6400;
  #pragma unroll
  for (int i = 0; i < 25; i++){
    int j = t + 256*i;
    int d = j / 100, p = j - d*100;
    lds[d*101 + p] = fp[j];
  }
  __syncthreads();
  if (t < 100){
    float ss = 0.f;
    #pragma unroll
    for (int d = 0; d < 64; d++){ float x = lds[d*101 + t]; ss += x*x; }
    inv[t] = 1.f / fmaxf(sqrtf(ss), 1e-12f);
  }
  __syncthreads();
  #pragma unroll
  for (int i = 0; i < 25; i++){
    int j = t + 256*i;
    int p = j >> 6, d = j & 63;
    vptS[(size_t)s*6400 + j] = lds[d*101 + p] * inv[p];
  }
}

// ---------------- kVb: sum 5 shots -> vpt ([p][d]) + B2 ([f][72], f=d*100+p) ----------------
// grid 1750: pair = b/25, j-chunk = (b%25)*256
__global__ __launch_bounds__(256) void kVb(const float* __restrict__ vptS,
                                           float* __restrict__ vpt,
                                           float* __restrict__ B2){
  __shared__ float l2[256];
  int b = blockIdx.x;
  int pair = b / 25, jc = b - pair*25;
  int n = pair / PRJ, v = pair - n*PRJ;
  int j0 = jc * 256;
  int t = threadIdx.x;
  int j = j0 + t;
  float s = 0.f;
  #pragma unroll
  for (int k = 0; k < KSHOT; k++){
    int sk = (n*KSHOT + k)*PRJ + v;
    s += vptS[(size_t)sk*6400 + j];
  }
  float val = s * 0.2f;
  vpt[(size_t)pair*6400 + j] = val;
  // mini-transpose: chunk covers p0..p0+3 (4 rows) x d 0..63
  int p = j >> 6, d = j & 63;
  int plocal = p & 3;
  l2[d*4 + plocal] = val;
  __syncthreads();
  if (t < 64){
    int p0 = j0 >> 6;
    float4 w4 = make_float4(l2[t*4+0], l2[t*4+1], l2[t*4+2], l2[t*4+3]);
    // f = t*100 + p0 .. +3 ; B2 row-major [f][72] -> 4 consecutive rows? No:
    // B2[f*72+pair] for f..f+3 -> stride 72; write scalar x4 (16B not contiguous)
    B2[(size_t)(t*100 + p0 + 0)*72 + pair] = w4.x;
    B2[(size_t)(t*100 + p0 + 1)*72 + pair] = w4.y;
    B2[(size_t)(t*100 + p0 + 2)*72 + pair] = w4.z;
    B2[(size_t)(t*100 + p0 + 3)*72 + pair] = w4.w;
  }
}

// ---------------- kVc: per-pair vninv + MM + psum from vpt (wave=pair) ----------------
__global__ __launch_bounds__(256) void kVc(const float* __restrict__ vpt,
                                           float* __restrict__ vninv,
                                           float* __restrict__ MM,
                                           float* __restrict__ psum){
  int t = threadIdx.x;
  int w = t >> 6, l = t & 63;
  int pair = blockIdx.x*4 + w;
  if (pair >= NPAIR) return;
  const float* vb = vpt + (size_t)pair*6400;
  float ps = 0.f, ss = 0.f;
  for (int p = 0; p < PP; p++){
    float x = vb[p*64 + l];
    ps += x;
    ss += x*x;
    float rm = redsum64(x);
    if (l == 0) MM[pair*100 + p] = rm * (1.f/64.f);
  }
  psum[pair*64 + l] = ps;
  float tot = redsum64(ss);
  if (l == 0) vninv[pair] = 1.f / fmaxf(sqrtf(tot), 1e-12f);
}

// ---------------- kB: tiny reduce of psum -> base ----------------
__global__ __launch_bounds__(320) void kB(const float* __restrict__ psum,
                                          float* __restrict__ base){
  int t = threadIdx.x;
  int n = t >> 6, d = t & 63;
  float s = 0.f;
  #pragma unroll
  for (int v = 0; v < PRJ; v++) s += psum[(n*PRJ + v)*64 + d];
  base[t] = s * (1.f/1400.f);
}

// ---------------- kQ: per-query inv norms + query_vec ----------------
__global__ __launch_bounds__(256) void kQ(const float* __restrict__ feat,
                                          float* __restrict__ invq,
                                          float* __restrict__ qv){
  __shared__ float lds[64*101];
  __shared__ float inv[100];
  int q = blockIdx.x, t = threadIdx.x;
  const float* fp = feat + (size_t)(NS + q) * 6400;
  #pragma unroll
  for (int i = 0; i < 25; i++){
    int j = t + 256*i;
    int d = j / 100, p = j - d*100;
    lds[d*101 + p] = fp[j];
  }
  __syncthreads();
  if (t < 100){
    float ss = 0.f;
    #pragma unroll
    for (int d = 0; d < 64; d++){ float x = lds[d*101 + t]; ss += x*x; }
    float iv = 1.f / fmaxf(sqrtf(ss), 1e-12f);
    inv[t] = iv;
    invq[q*100 + t] = iv;
  }
  __syncthreads();
  if (t < 64){
    float s = 0.f;
    for (int p = 0; p < PP; p++) s += lds[t*101 + p] * inv[p];
    qv[q*64 + t] = s * 0.01f;
  }
}

// ---------------- kS: lane=query, scalar-B FMA, f-split 32 ----------------
__global__ __launch_bounds__(256) void kS(const float* __restrict__ feat,
                                          const float* __restrict__ invq,
                                          const float* __restrict__ B2,
                                          float* __restrict__ sim32){
  __shared__ float A[100*66];
  int b = blockIdx.x;
  int qg = b & 15, fg = b >> 4;
  int q0 = qg * 64;
  int t = threadIdx.x;
  int l = t & 63;
  int wu = __builtin_amdgcn_readfirstlane(t >> 6);
  int pr0 = wu * 18;

  float acc[18];
  #pragma unroll
  for (int j = 0; j < 18; j++) acc[j] = 0.f;

  for (int cc = 0; cc < SUBCH; cc++){
    int fbase = (fg*SUBCH + cc) * 100;
    __syncthreads();
    for (int i = t; i < 1600; i += 256){
      int q = i / 25, r4 = i - q*25;
      float4 f4 = *(const float4*)(feat + (size_t)(NS + q0 + q)*6400 + fbase + r4*4);
      float4 v4 = *(const float4*)(invq + (q0 + q)*100 + r4*4);
      A[(r4*4+0)*66 + q] = f4.x * v4.x;
      A[(r4*4+1)*66 + q] = f4.y * v4.y;
      A[(r4*4+2)*66 + q] = f4.z * v4.z;
      A[(r4*4+3)*66 + q] = f4.w * v4.w;
    }
    __syncthreads();
    const float* Bb = B2 + (size_t)fbase*72 + pr0;   // wave-uniform -> s_load
    for (int r = 0; r < 100; r++){
      float a = A[r*66 + l];
      #pragma unroll
      for (int j = 0; j < 18; j++)
        acc[j] += a * Bb[r*72 + j];
    }
  }
  int qq = q0 + l;
  #pragma unroll
  for (int j = 0; j < 18; j++){
    int pr = pr0 + j;
    if (pr < NPAIR) sim32[(size_t)fg*SIM_STRIDE + qq*NPAIR + pr] = acc[j];
  }
}

// ---------------- kSr: reduce 32 f-group partials -> sim ----------------
__global__ __launch_bounds__(256) void kSr(const float* __restrict__ sim32,
                                           float* __restrict__ sim){
  int idx = blockIdx.x*256 + threadIdx.x;
  float s = 0.f;
  #pragma unroll
  for (int c = 0; c < FGROUPS; c++) s += sim32[(size_t)c*SIM_STRIDE + idx];
  sim[idx] = s;
}

// ---------------- kM: per-(q,n) softmax over 14 views ----------------
__global__ __launch_bounds__(256) void kM(const float* __restrict__ sim,
                                          const float* __restrict__ vninv,
                                          const float* __restrict__ temp,
                                          float* __restrict__ pw){
  int t = blockIdx.x*256 + threadIdx.x;
  if (t >= NQ*NWAY) return;
  int q = t / NWAY, n = t - q*NWAY;
  float invT = 1.f / (temp[0] + 1e-6f);
  float s[PRJ];
  float m = -3.4e38f;
  #pragma unroll
  for (int v = 0; v < PRJ; v++){
    int pr = n*PRJ + v;
    s[v] = sim[q*NPAIR + pr] * vninv[pr] * invT;
    m = fmaxf(m, s[v]);
  }
  float sum = 0.f;
  #pragma unroll
  for (int v = 0; v < PRJ; v++){ s[v] = expf(s[v] - m); sum += s[v]; }
  float rs = 1.f / sum;
  #pragma unroll
  for (int v = 0; v < PRJ; v++) pw[q*NPAIR + n*PRJ + v] = s[v] * rs;
}

// ---------------- kP: p-split 4x, sg computed inline, partial outputs ----------------
__global__ __launch_bounds__(256) void kP(const float* __restrict__ vpt,
                                          const float* __restrict__ pw,
                                          const float* __restrict__ MM,
                                          float* __restrict__ pq4){
  __shared__ float sgl[16][PCHUNK];
  int b = blockIdx.x;
  int n  = b / 256;
  int r  = b - n*256;
  int qb = r >> 2;
  int s  = r & 3;
  int p0 = s * PCHUNK;
  int t = threadIdx.x, w = t >> 6, l = t & 63;
  int q0 = qb*16 + w*4;

  float wq[4][PRJ];
  #pragma unroll
  for (int j = 0; j < 4; j++)
    #pragma unroll
    for (int v = 0; v < PRJ; v++)
      wq[j][v] = pw[(q0+j)*NPAIR + n*PRJ + v];

  if (l < PCHUNK){
    #pragma unroll
    for (int j = 0; j < 4; j++){
      float ssg = 0.f;
      #pragma unroll
      for (int v = 0; v < PRJ; v++)
        ssg += wq[j][v] * MM[(n*PRJ + v)*100 + p0 + l];
      sgl[w*4 + j][l] = 1.f / (1.f + expf(-ssg));
    }
  }
  __syncthreads();

  float acc[4] = {0.f, 0.f, 0.f, 0.f};
  const float* vb = vpt + (size_t)n * PRJ * 6400;
  for (int pl = 0; pl < PCHUNK; pl++){
    int p = p0 + pl;
    float vv[PRJ];
    #pragma unroll
    for (int v = 0; v < PRJ; v++) vv[v] = vb[v*6400 + p*64 + l];
    #pragma unroll
    for (int j = 0; j < 4; j++){
      float dot = 0.f;
      #pragma unroll
      for (int v = 0; v < PRJ; v++) dot += wq[j][v] * vv[v];
      acc[j] += sgl[w*4 + j][pl] * dot;
    }
  }
  #pragma unroll
  for (int j = 0; j < 4; j++)
    pq4[(size_t)s*PQ_ELEMS + ((q0+j)*NWAY + n)*64 + l] = acc[j];
}

// ---------------- kPr: reduce 4 p-split partials ----------------
__global__ __launch_bounds__(256) void kPr(const float* __restrict__ pq4,
                                           float* __restrict__ pq){
  int idx = blockIdx.x*256 + threadIdx.x;
  float s = pq4[idx] + pq4[PQ_ELEMS + idx] + pq4[2*PQ_ELEMS + idx] + pq4[3*PQ_ELEMS + idx];
  pq[idx] = s;
}

// ---------------- kF v2: 5 waves per query, wave = n ----------------
__global__ __launch_bounds__(320) void kF(const float* __restrict__ qv,
                                          const float* __restrict__ pqw,
                                          const float* __restrict__ base,
                                          const float* __restrict__ Wq,
                                          const float* __restrict__ bq,
                                          const float* __restrict__ Wk,
                                          const float* __restrict__ bk,
                                          const float* __restrict__ gate,
                                          const int*   __restrict__ label,
                                          float* __restrict__ pred,
                                          float* __restrict__ cls,
                                          float* __restrict__ aln){
  __shared__ float qvl[64];
  __shared__ float qp[16];
  __shared__ float scn[NWAY], cosn[NWAY], c2n[NWAY];
  __shared__ float dl5[NWAY][64];
  int q = blockIdx.x, t = threadIdx.x;
  int w = t >> 6, l = t & 63;      // w = n

  float qvv = qv[q*64 + l];
  float qss = redsum64(qvv*qvv);
  float qn8 = fmaxf(sqrtf(qss), 1e-8f);
  if (w == 0) qvl[l] = qvv;
  __syncthreads();
  if (w == 0 && l < 16){
    float s = bq[l];
    #pragma unroll
    for (int d = 0; d < 64; d++) s += qvl[d] * Wq[d*16 + l];
    qp[l] = s;
  }
  __syncthreads();

  float wkq = 0.f;
  #pragma unroll
  for (int e = 0; e < 16; e++) wkq += Wk[l*16 + e] * qp[e];
  float qpb = 0.f;
  #pragma unroll
  for (int e = 0; e < 16; e++) qpb += qp[e] * bk[e];

  // this wave's n = w
  float x = pqw[(q*NWAY + w)*64 + l];
  float dq = redsum64(qvv * x);
  float ps = redsum64(x * x);
  float cosw = dq / (qn8 * fmaxf(sqrtf(ps), 1e-8f));
  float sd = redsum64(x * wkq);
  float scw = (sd + qpb) * 0.25f;
  if (l == 0){ scn[w] = scw; cosn[w] = cosw; }
  __syncthreads();

  // attn softmax over n (redundant per thread)
  float am = scn[0];
  #pragma unroll
  for (int n = 1; n < NWAY; n++) am = fmaxf(am, scn[n]);
  float asum = 0.f;
  #pragma unroll
  for (int n = 0; n < NWAY; n++) asum += expf(scn[n] - am);
  float attw = expf(scw - am) / asum;

  // gate band weights
  float g0 = gate[0], g1 = gate[1], g2 = gate[2];
  float gm = fmaxf(fmaxf(g0, g1), g2);
  float e0 = expf(g0 - gm), e1 = expf(g1 - gm), e2 = expf(g2 - gm);
  float gs = 1.f / (e0 + e1 + e2);
  float b0 = (e0 + e1 + e2) * gs;
  float b1 = (e1 + e2) * gs;
  float b2 = e2 * gs;

  // DeltaGate for this wave's n
  float f  = x * attw;
  float dd = fabsf(f - base[w*64 + l]);
  dl5[w][l] = dd;
  int rank = 0;
  #pragma unroll 8
  for (int j = 0; j < 64; j++){
    float dj = dl5[w][j];
    rank += (dj > dd) || (dj == dd && j < l);
  }
  float cw = (rank < 16) ? b0 : (rank < 32) ? b1 : (rank < 48) ? b2 : 0.f;
  float gl = f * cw;
  float gss = redsum64(gl * gl);
  float num = redsum64(qvv * gl);
  float c2w = num / (qn8 * fmaxf(sqrtf(gss), 1e-12f));
  if (l == 0) c2n[w] = c2w;
  __syncthreads();

  // pred softmax over n (each wave writes its own n)
  float mx = c2n[0];
  #pragma unroll
  for (int n = 1; n < NWAY; n++) mx = fmaxf(mx, c2n[n]);
  float psum2 = 0.f;
  #pragma unroll
  for (int n = 0; n < NWAY; n++) psum2 += expf(c2n[n] - mx);
  if (l == 0) pred[q*NWAY + w] = expf(c2w - mx) / psum2;

  if (t == 0){
    int lab = label[q];
    float lm = LAMDA * mx;
    float lsum = 0.f;
    #pragma unroll
    for (int n = 0; n < NWAY; n++) lsum += expf(LAMDA * c2n[n] - lm);
    float c2l = c2n[lab], cosl = cosn[lab];
    float clsv = (lm + logf(lsum)) - LAMDA * c2l;
    float sum5 = 0.f, minn = 3.4e38f;
    #pragma unroll
    for (int n = 0; n < NWAY; n++){
      sum5 += cosn[n];
      if (n != lab) minn = fminf(minn, cosn[n]);
    }
    float hn = (sum5 - cosl - minn) * (1.f/3.f);
    float al = fmaxf(hn - cosl + MARGIN, 0.f);
    cls[q] = clsv; aln[q] = al;
  }
}

// ---------------- kL: loss reduction ----------------
__global__ __launch_bounds__(256) void kL(const float* __restrict__ cls,
                                          const float* __restrict__ aln,
                                          float* __restrict__ out){
  __shared__ float r1[256], r2[256];
  int t = threadIdx.x;
  float s1 = 0.f, s2 = 0.f;
  for (int i = t; i < NQ; i += 256){ s1 += cls[i]; s2 += aln[i]; }
  r1[t] = s1; r2[t] = s2;
  __syncthreads();
  for (int o = 128; o > 0; o >>= 1){
    if (t < o){ r1[t] += r1[t + o]; r2[t] += r2[t + o]; }
    __syncthreads();
  }
  if (t == 0)
    out[NQ*NWAY] = r1[0]*(1.f/NQ) + 0.3f*(r2[0]*(1.f/NQ));
}

extern "C" void kernel_launch(void* const* d_in, const int* in_sizes, int n_in,
                              void* d_out, int out_size, void* d_ws, size_t ws_size,
                              hipStream_t stream){
  const float* feat = (const float*)d_in[0];
  const float* temp = (const float*)d_in[1];
  const float* gate = (const float*)d_in[2];
  const float* Wq   = (const float*)d_in[3];
  const float* bq   = (const float*)d_in[4];
  const float* Wk   = (const float*)d_in[5];
  const float* bk   = (const float*)d_in[6];
  const int*   lab  = (const int*)d_in[7];
  float* out = (float*)d_out;
  float* ws  = (float*)d_ws;

  float* vpt   = ws + VPT_OFF;
  float* vptS  = ws + VPTS_OFF;
  float* B2    = ws + B2_OFF;
  float* MMp   = ws + MM_OFF;
  float* vninv = ws + VNINV_OFF;
  float* psum  = ws + PSUM_OFF;
  float* base  = ws + BASE_OFF;
  float* qv    = ws + QV_OFF;
  float* invq  = ws + INVQ_OFF;
  float* sim32 = ws + SIM32_OFF;
  float* sim   = ws + SIM_OFF;
  float* pw    = ws + PW_OFF;
  float* pq4   = ws + PQ4_OFF;
  float* pq    = ws + PQ_OFF;
  float* cls   = ws + CLS_OFF;
  float* aln   = ws + ALN_OFF;

  hipLaunchKernelGGL(kVa, dim3(NS), dim3(256), 0, stream, feat, vptS);
  hipLaunchKernelGGL(kVb, dim3(NPAIR*25), dim3(256), 0, stream, vptS, vpt, B2);
  hipLaunchKernelGGL(kVc, dim3(18), dim3(256), 0, stream, vpt, vninv, MMp, psum);
  hipLaunchKernelGGL(kB, dim3(1), dim3(320), 0, stream, psum, base);
  hipLaunchKernelGGL(kQ, dim3(NQ), dim3(256), 0, stream, feat, invq, qv);
  hipLaunchKernelGGL(kS, dim3(16*FGROUPS), dim3(256), 0, stream, feat, invq, B2, sim32);
  hipLaunchKernelGGL(kSr, dim3(NQ*NPAIR/256), dim3(256), 0, stream, sim32, sim);
  hipLaunchKernelGGL(kM, dim3((NQ*NWAY + 255)/256), dim3(256), 0, stream, sim, vninv, temp, pw);
  hipLaunchKernelGGL(kP, dim3(NWAY*256), dim3(256), 0, stream, vpt, pw, MMp, pq4);
  hipLaunchKernelGGL(kPr, dim3(PQ_ELEMS/256), dim3(256), 0, stream, pq4, pq);
  hipLaunchKernelGGL(kF, dim3(NQ), dim3(320), 0, stream, qv, pq, base, Wq, bq, Wk, bk, gate, lab, out, cls, aln);
  hipLaunchKernelGGL(kL, dim3(1), dim3(256), 0, stream, cls, aln, out);
}

// Round 8
// 128.369 us; speedup vs baseline: 1.3590x; 1.3590x over previous
//
#include <hip/hip_runtime.h>
#include <math.h>

#define NWAY 5
#define KSHOT 5
#define PRJ 14
#define DD 64
#define PP 100
#define NQ 1024
#define NS 350
#define NPAIR 70
#define LAMDA 32.0f
#define MARGIN 0.3f
#define PCHUNK 25
#define FGROUPS 32
#define SUBCH 2

// ---- workspace layout (floats), ~30.1 MB ----
#define VPT_OFF   0          // [70][100][64]  = 448000  ([p][d])
#define VPTS_OFF  448000     // [350][6400]    = 2240000
#define B2_OFF    2688000    // [6400][72]     = 460800
#define MM_OFF    3148800    // [70][100]      = 7000
#define VNINV_OFF 3155800    // [70] pad 128
#define PSUM_OFF  3155928    // [70][64] = 4480
#define BASE_OFF  3160408    // [5][64]
#define QV_OFF    3160728    // [1024][64] = 65536
#define INVQ_OFF  3226264    // [1024][100] = 102400
#define SIM32_OFF 3328664    // [32][1024][70] = 2293760
#define SIM_OFF   5622424    // [1024][70] = 71680
#define PW_OFF    5694104    // [1024][70] = 71680
#define PQ4_OFF   5765784    // [4][1024][5][64] = 1310720
#define PQ_OFF    7076504    // [1024][5][64] = 327680
#define CLS_OFF   7404184    // [1024]
#define ALN_OFF   7405208    // [1024]
#define PSUMP_OFF 7406232    // [70][25][64] = 112000
#define SSQP_OFF  7518232    // [70][25] pad

#define PQ_ELEMS (NQ*NWAY*64)
#define SIM_STRIDE (NQ*NPAIR)

__device__ __forceinline__ float redsum64(float x){
  #pragma unroll
  for (int o = 1; o < 64; o <<= 1) x += __shfl_xor(x, o, 64);
  return x;
}

// ---------------- kVa: one block per support sample -> per-position L2 normalize ----------------
__global__ __launch_bounds__(256) void kVa(const float* __restrict__ feat,
                                           float* __restrict__ vptS){
  __shared__ float lds[64*101];
  __shared__ float inv[100];
  int s = blockIdx.x, t = threadIdx.x;
  const float* fp = feat + (size_t)s * 6400;
  #pragma unroll
  for (int i = 0; i < 25; i++){
    int j = t + 256*i;
    int d = j / 100, p = j - d*100;
    lds[d*101 + p] = fp[j];
  }
  __syncthreads();
  if (t < 100){
    float ss = 0.f;
    #pragma unroll
    for (int d = 0; d < 64; d++){ float x = lds[d*101 + t]; ss += x*x; }
    inv[t] = 1.f / fmaxf(sqrtf(ss), 1e-12f);
  }
  __syncthreads();
  #pragma unroll
  for (int i = 0; i < 25; i++){
    int j = t + 256*i;
    int p = j >> 6, d = j & 63;
    vptS[(size_t)s*6400 + j] = lds[d*101 + p] * inv[p];
  }
}

// ---------------- kVb v2: sum 5 shots -> vpt + B2 + MM + psumP + ssqP ----------------
// grid 1750: pair = b/25, chunk jc = b%25 (4 p's x 64 d)
__global__ __launch_bounds__(256) void kVb(const float* __restrict__ vptS,
                                           float* __restrict__ vpt,
                                           float* __restrict__ B2,
                                           float* __restrict__ MM,
                                           float* __restrict__ psumP,
                                           float* __restrict__ ssqP){
  __shared__ float l2[256];
  __shared__ float wssq[4];
  int b = blockIdx.x;
  int pair = b / 25, jc = b - pair*25;
  int n = pair / PRJ, v = pair - n*PRJ;
  int j0 = jc * 256;
  int t = threadIdx.x;
  int j = j0 + t;
  float s = 0.f;
  #pragma unroll
  for (int k = 0; k < KSHOT; k++){
    int sk = (n*KSHOT + k)*PRJ + v;
    s += vptS[(size_t)sk*6400 + j];
  }
  float val = s * 0.2f;
  vpt[(size_t)pair*6400 + j] = val;
  int p = j >> 6, d = j & 63;
  int plocal = p & 3;
  l2[d*4 + plocal] = val;
  float sq = redsum64(val*val);
  if ((t & 63) == 0) wssq[t >> 6] = sq;
  __syncthreads();
  if (t < 64){
    int p0 = j0 >> 6;
    float4 w4 = make_float4(l2[t*4+0], l2[t*4+1], l2[t*4+2], l2[t*4+3]);
    B2[(size_t)(t*100 + p0 + 0)*72 + pair] = w4.x;
    B2[(size_t)(t*100 + p0 + 1)*72 + pair] = w4.y;
    B2[(size_t)(t*100 + p0 + 2)*72 + pair] = w4.z;
    B2[(size_t)(t*100 + p0 + 3)*72 + pair] = w4.w;
    // psum partial over this chunk's 4 p's, per d
    psumP[((size_t)pair*25 + jc)*64 + t] = w4.x + w4.y + w4.z + w4.w;
  }
  if (t >= 128 && t < 132){
    int i = t - 128;
    float m = 0.f;
    #pragma unroll
    for (int dd2 = 0; dd2 < 64; dd2++) m += l2[dd2*4 + i];
    MM[pair*100 + (j0 >> 6) + i] = m * (1.f/64.f);
  }
  if (t == 192)
    ssqP[pair*25 + jc] = wssq[0] + wssq[1] + wssq[2] + wssq[3];
}

// ---------------- kVc2: reduce chunk partials -> psum + vninv ----------------
__global__ __launch_bounds__(64) void kVc2(const float* __restrict__ psumP,
                                           const float* __restrict__ ssqP,
                                           float* __restrict__ psum,
                                           float* __restrict__ vninv){
  int pair = blockIdx.x, l = threadIdx.x;
  float s = 0.f;
  #pragma unroll
  for (int c = 0; c < 25; c++) s += psumP[((size_t)pair*25 + c)*64 + l];
  psum[pair*64 + l] = s;
  float sq = (l < 25) ? ssqP[pair*25 + l] : 0.f;
  float tot = redsum64(sq);
  if (l == 0) vninv[pair] = 1.f / fmaxf(sqrtf(tot), 1e-12f);
}

// ---------------- kB: tiny reduce of psum -> base ----------------
__global__ __launch_bounds__(320) void kB(const float* __restrict__ psum,
                                          float* __restrict__ base){
  int t = threadIdx.x;
  int n = t >> 6, d = t & 63;
  float s = 0.f;
  #pragma unroll
  for (int v = 0; v < PRJ; v++) s += psum[(n*PRJ + v)*64 + d];
  base[t] = s * (1.f/1400.f);
}

// ---------------- kQ: per-query inv norms + query_vec ----------------
__global__ __launch_bounds__(256) void kQ(const float* __restrict__ feat,
                                          float* __restrict__ invq,
                                          float* __restrict__ qv){
  __shared__ float lds[64*101];
  __shared__ float inv[100];
  int q = blockIdx.x, t = threadIdx.x;
  const float* fp = feat + (size_t)(NS + q) * 6400;
  #pragma unroll
  for (int i = 0; i < 25; i++){
    int j = t + 256*i;
    int d = j / 100, p = j - d*100;
    lds[d*101 + p] = fp[j];
  }
  __syncthreads();
  if (t < 100){
    float ss = 0.f;
    #pragma unroll
    for (int d = 0; d < 64; d++){ float x = lds[d*101 + t]; ss += x*x; }
    float iv = 1.f / fmaxf(sqrtf(ss), 1e-12f);
    inv[t] = iv;
    invq[q*100 + t] = iv;
  }
  __syncthreads();
  if (t < 64){
    float s = 0.f;
    for (int p = 0; p < PP; p++) s += lds[t*101 + p] * inv[p];
    qv[q*64 + t] = s * 0.01f;
  }
}

// ---------------- kS: lane=query, scalar-B FMA, f-split 32 ----------------
__global__ __launch_bounds__(256) void kS(const float* __restrict__ feat,
                                          const float* __restrict__ invq,
                                          const float* __restrict__ B2,
                                          float* __restrict__ sim32){
  __shared__ float A[100*66];
  int b = blockIdx.x;
  int qg = b & 15, fg = b >> 4;
  int q0 = qg * 64;
  int t = threadIdx.x;
  int l = t & 63;
  int wu = __builtin_amdgcn_readfirstlane(t >> 6);
  int pr0 = wu * 18;

  float acc[18];
  #pragma unroll
  for (int j = 0; j < 18; j++) acc[j] = 0.f;

  for (int cc = 0; cc < SUBCH; cc++){
    int fbase = (fg*SUBCH + cc) * 100;
    __syncthreads();
    for (int i = t; i < 1600; i += 256){
      int q = i / 25, r4 = i - q*25;
      float4 f4 = *(const float4*)(feat + (size_t)(NS + q0 + q)*6400 + fbase + r4*4);
      float4 v4 = *(const float4*)(invq + (q0 + q)*100 + r4*4);
      A[(r4*4+0)*66 + q] = f4.x * v4.x;
      A[(r4*4+1)*66 + q] = f4.y * v4.y;
      A[(r4*4+2)*66 + q] = f4.z * v4.z;
      A[(r4*4+3)*66 + q] = f4.w * v4.w;
    }
    __syncthreads();
    const float* Bb = B2 + (size_t)fbase*72 + pr0;   // wave-uniform -> s_load
    for (int r = 0; r < 100; r++){
      float a = A[r*66 + l];
      #pragma unroll
      for (int j = 0; j < 18; j++)
        acc[j] += a * Bb[r*72 + j];
    }
  }
  int qq = q0 + l;
  #pragma unroll
  for (int j = 0; j < 18; j++){
    int pr = pr0 + j;
    if (pr < NPAIR) sim32[(size_t)fg*SIM_STRIDE + qq*NPAIR + pr] = acc[j];
  }
}

// ---------------- kSr: reduce 32 f-group partials -> sim ----------------
__global__ __launch_bounds__(256) void kSr(const float* __restrict__ sim32,
                                           float* __restrict__ sim){
  int idx = blockIdx.x*256 + threadIdx.x;
  float s = 0.f;
  #pragma unroll
  for (int c = 0; c < FGROUPS; c++) s += sim32[(size_t)c*SIM_STRIDE + idx];
  sim[idx] = s;
}

// ---------------- kM: per-(q,n) softmax over 14 views ----------------
__global__ __launch_bounds__(256) void kM(const float* __restrict__ sim,
                                          const float* __restrict__ vninv,
                                          const float* __restrict__ temp,
                                          float* __restrict__ pw){
  int t = blockIdx.x*256 + threadIdx.x;
  if (t >= NQ*NWAY) return;
  int q = t / NWAY, n = t - q*NWAY;
  float invT = 1.f / (temp[0] + 1e-6f);
  float s[PRJ];
  float m = -3.4e38f;
  #pragma unroll
  for (int v = 0; v < PRJ; v++){
    int pr = n*PRJ + v;
    s[v] = sim[q*NPAIR + pr] * vninv[pr] * invT;
    m = fmaxf(m, s[v]);
  }
  float sum = 0.f;
  #pragma unroll
  for (int v = 0; v < PRJ; v++){ s[v] = expf(s[v] - m); sum += s[v]; }
  float rs = 1.f / sum;
  #pragma unroll
  for (int v = 0; v < PRJ; v++) pw[q*NPAIR + n*PRJ + v] = s[v] * rs;
}

// ---------------- kP: p-split 4x, sg computed inline, partial outputs ----------------
__global__ __launch_bounds__(256) void kP(const float* __restrict__ vpt,
                                          const float* __restrict__ pw,
                                          const float* __restrict__ MM,
                                          float* __restrict__ pq4){
  __shared__ float sgl[16][PCHUNK];
  int b = blockIdx.x;
  int n  = b / 256;
  int r  = b - n*256;
  int qb = r >> 2;
  int s  = r & 3;
  int p0 = s * PCHUNK;
  int t = threadIdx.x, w = t >> 6, l = t & 63;
  int q0 = qb*16 + w*4;

  float wq[4][PRJ];
  #pragma unroll
  for (int j = 0; j < 4; j++)
    #pragma unroll
    for (int v = 0; v < PRJ; v++)
      wq[j][v] = pw[(q0+j)*NPAIR + n*PRJ + v];

  if (l < PCHUNK){
    #pragma unroll
    for (int j = 0; j < 4; j++){
      float ssg = 0.f;
      #pragma unroll
      for (int v = 0; v < PRJ; v++)
        ssg += wq[j][v] * MM[(n*PRJ + v)*100 + p0 + l];
      sgl[w*4 + j][l] = 1.f / (1.f + expf(-ssg));
    }
  }
  __syncthreads();

  float acc[4] = {0.f, 0.f, 0.f, 0.f};
  const float* vb = vpt + (size_t)n * PRJ * 6400;
  for (int pl = 0; pl < PCHUNK; pl++){
    int p = p0 + pl;
    float vv[PRJ];
    #pragma unroll
    for (int v = 0; v < PRJ; v++) vv[v] = vb[v*6400 + p*64 + l];
    #pragma unroll
    for (int j = 0; j < 4; j++){
      float dot = 0.f;
      #pragma unroll
      for (int v = 0; v < PRJ; v++) dot += wq[j][v] * vv[v];
      acc[j] += sgl[w*4 + j][pl] * dot;
    }
  }
  #pragma unroll
  for (int j = 0; j < 4; j++)
    pq4[(size_t)s*PQ_ELEMS + ((q0+j)*NWAY + n)*64 + l] = acc[j];
}

// ---------------- kPr: reduce 4 p-split partials ----------------
__global__ __launch_bounds__(256) void kPr(const float* __restrict__ pq4,
                                           float* __restrict__ pq){
  int idx = blockIdx.x*256 + threadIdx.x;
  float s = pq4[idx] + pq4[PQ_ELEMS + idx] + pq4[2*PQ_ELEMS + idx] + pq4[3*PQ_ELEMS + idx];
  pq[idx] = s;
}

// ---------------- kF: 5 waves per query, wave = n ----------------
__global__ __launch_bounds__(320) void kF(const float* __restrict__ qv,
                                          const float* __restrict__ pqw,
                                          const float* __restrict__ base,
                                          const float* __restrict__ Wq,
                                          const float* __restrict__ bq,
                                          const float* __restrict__ Wk,
                                          const float* __restrict__ bk,
                                          const float* __restrict__ gate,
                                          const int*   __restrict__ label,
                                          float* __restrict__ pred,
                                          float* __restrict__ cls,
                                          float* __restrict__ aln){
  __shared__ float qvl[64];
  __shared__ float qp[16];
  __shared__ float scn[NWAY], cosn[NWAY], c2n[NWAY];
  __shared__ float dl5[NWAY][64];
  int q = blockIdx.x, t = threadIdx.x;
  int w = t >> 6, l = t & 63;      // w = n

  float qvv = qv[q*64 + l];
  float qss = redsum64(qvv*qvv);
  float qn8 = fmaxf(sqrtf(qss), 1e-8f);
  if (w == 0) qvl[l] = qvv;
  __syncthreads();
  if (w == 0 && l < 16){
    float s = bq[l];
    #pragma unroll
    for (int d = 0; d < 64; d++) s += qvl[d] * Wq[d*16 + l];
    qp[l] = s;
  }
  __syncthreads();

  float wkq = 0.f;
  #pragma unroll
  for (int e = 0; e < 16; e++) wkq += Wk[l*16 + e] * qp[e];
  float qpb = 0.f;
  #pragma unroll
  for (int e = 0; e < 16; e++) qpb += qp[e] * bk[e];

  float x = pqw[(q*NWAY + w)*64 + l];
  float dq = redsum64(qvv * x);
  float ps = redsum64(x * x);
  float cosw = dq / (qn8 * fmaxf(sqrtf(ps), 1e-8f));
  float sd = redsum64(x * wkq);
  float scw = (sd + qpb) * 0.25f;
  if (l == 0){ scn[w] = scw; cosn[w] = cosw; }
  __syncthreads();

  float am = scn[0];
  #pragma unroll
  for (int n = 1; n < NWAY; n++) am = fmaxf(am, scn[n]);
  float asum = 0.f;
  #pragma unroll
  for (int n = 0; n < NWAY; n++) asum += expf(scn[n] - am);
  float attw = expf(scw - am) / asum;

  float g0 = gate[0], g1 = gate[1], g2 = gate[2];
  float gm = fmaxf(fmaxf(g0, g1), g2);
  float e0 = expf(g0 - gm), e1 = expf(g1 - gm), e2 = expf(g2 - gm);
  float gs = 1.f / (e0 + e1 + e2);
  float b0 = (e0 + e1 + e2) * gs;
  float b1 = (e1 + e2) * gs;
  float b2 = e2 * gs;

  float f  = x * attw;
  float dd = fabsf(f - base[w*64 + l]);
  dl5[w][l] = dd;
  int rank = 0;
  #pragma unroll 8
  for (int j = 0; j < 64; j++){
    float dj = dl5[w][j];
    rank += (dj > dd) || (dj == dd && j < l);
  }
  float cw = (rank < 16) ? b0 : (rank < 32) ? b1 : (rank < 48) ? b2 : 0.f;
  float gl = f * cw;
  float gss = redsum64(gl * gl);
  float num = redsum64(qvv * gl);
  float c2w = num / (qn8 * fmaxf(sqrtf(gss), 1e-12f));
  if (l == 0) c2n[w] = c2w;
  __syncthreads();

  float mx = c2n[0];
  #pragma unroll
  for (int n = 1; n < NWAY; n++) mx = fmaxf(mx, c2n[n]);
  float psum2 = 0.f;
  #pragma unroll
  for (int n = 0; n < NWAY; n++) psum2 += expf(c2n[n] - mx);
  if (l == 0) pred[q*NWAY + w] = expf(c2w - mx) / psum2;

  if (t == 0){
    int lab = label[q];
    float lm = LAMDA * mx;
    float lsum = 0.f;
    #pragma unroll
    for (int n = 0; n < NWAY; n++) lsum += expf(LAMDA * c2n[n] - lm);
    float c2l = c2n[lab], cosl = cosn[lab];
    float clsv = (lm + logf(lsum)) - LAMDA * c2l;
    float sum5 = 0.f, minn = 3.4e38f;
    #pragma unroll
    for (int n = 0; n < NWAY; n++){
      sum5 += cosn[n];
      if (n != lab) minn = fminf(minn, cosn[n]);
    }
    float hn = (sum5 - cosl - minn) * (1.f/3.f);
    float al = fmaxf(hn - cosl + MARGIN, 0.f);
    cls[q] = clsv; aln[q] = al;
  }
}

// ---------------- kL: loss reduction ----------------
__global__ __launch_bounds__(256) void kL(const float* __restrict__ cls,
                                          const float* __restrict__ aln,
                                          float* __restrict__ out){
  __shared__ float r1[256], r2[256];
  int t = threadIdx.x;
  float s1 = 0.f, s2 = 0.f;
  for (int i = t; i < NQ; i += 256){ s1 += cls[i]; s2 += aln[i]; }
  r1[t] = s1; r2[t] = s2;
  __syncthreads();
  for (int o = 128; o > 0; o >>= 1){
    if (t < o){ r1[t] += r1[t + o]; r2[t] += r2[t + o]; }
    __syncthreads();
  }
  if (t == 0)
    out[NQ*NWAY] = r1[0]*(1.f/NQ) + 0.3f*(r2[0]*(1.f/NQ));
}

extern "C" void kernel_launch(void* const* d_in, const int* in_sizes, int n_in,
                              void* d_out, int out_size, void* d_ws, size_t ws_size,
                              hipStream_t stream){
  const float* feat = (const float*)d_in[0];
  const float* temp = (const float*)d_in[1];
  const float* gate = (const float*)d_in[2];
  const float* Wq   = (const float*)d_in[3];
  const float* bq   = (const float*)d_in[4];
  const float* Wk   = (const float*)d_in[5];
  const float* bk   = (const float*)d_in[6];
  const int*   lab  = (const int*)d_in[7];
  float* out = (float*)d_out;
  float* ws  = (float*)d_ws;

  float* vpt   = ws + VPT_OFF;
  float* vptS  = ws + VPTS_OFF;
  float* B2    = ws + B2_OFF;
  float* MMp   = ws + MM_OFF;
  float* vninv = ws + VNINV_OFF;
  float* psum  = ws + PSUM_OFF;
  float* base  = ws + BASE_OFF;
  float* qv    = ws + QV_OFF;
  float* invq  = ws + INVQ_OFF;
  float* sim32 = ws + SIM32_OFF;
  float* sim   = ws + SIM_OFF;
  float* pw    = ws + PW_OFF;
  float* pq4   = ws + PQ4_OFF;
  float* pq    = ws + PQ_OFF;
  float* cls   = ws + CLS_OFF;
  float* aln   = ws + ALN_OFF;
  float* psumP = ws + PSUMP_OFF;
  float* ssqP  = ws + SSQP_OFF;

  hipLaunchKernelGGL(kVa, dim3(NS), dim3(256), 0, stream, feat, vptS);
  hipLaunchKernelGGL(kVb, dim3(NPAIR*25), dim3(256), 0, stream, vptS, vpt, B2, MMp, psumP, ssqP);
  hipLaunchKernelGGL(kVc2, dim3(NPAIR), dim3(64), 0, stream, psumP, ssqP, psum, vninv);
  hipLaunchKernelGGL(kB, dim3(1), dim3(320), 0, stream, psum, base);
  hipLaunchKernelGGL(kQ, dim3(NQ), dim3(256), 0, stream, feat, invq, qv);
  hipLaunchKernelGGL(kS, dim3(16*FGROUPS), dim3(256), 0, stream, feat, invq, B2, sim32);
  hipLaunchKernelGGL(kSr, dim3(NQ*NPAIR/256), dim3(256), 0, stream, sim32, sim);
  hipLaunchKernelGGL(kM, dim3((NQ*NWAY + 255)/256), dim3(256), 0, stream, sim, vninv, temp, pw);
  hipLaunchKernelGGL(kP, dim3(NWAY*256), dim3(256), 0, stream, vpt, pw, MMp, pq4);
  hipLaunchKernelGGL(kPr, dim3(PQ_ELEMS/256), dim3(256), 0, stream, pq4, pq);
  hipLaunchKernelGGL(kF, dim3(NQ), dim3(320), 0, stream, qv, pq, base, Wq, bq, Wk, bk, gate, lab, out, cls, aln);
  hipLaunchKernelGGL(kL, dim3(1), dim3(256), 0, stream, cls, aln, out);
}

// Round 9
// 116.879 us; speedup vs baseline: 1.4926x; 1.0983x over previous
//
#include <hip/hip_runtime.h>
#include <math.h>

#define NWAY 5
#define KSHOT 5
#define PRJ 14
#define DD 64
#define PP 100
#define NQ 1024
#define NS 350
#define NPAIR 70
#define LAMDA 32.0f
#define MARGIN 0.3f
#define PCHUNK 25
#define FGROUPS 32
#define SUBCH 2

// ---- workspace layout (floats) ----
#define VPT_OFF   0          // [70][100][64]  = 448000  ([p][d])
#define VPTS_OFF  448000     // [350][6400]    = 2240000
#define B2_OFF    2688000    // [6400][72]     = 460800
#define MM_OFF    3148800    // [70][100]      = 7000
#define VNINV_OFF 3155800    // [70] pad 128
#define PSUM_OFF  3155928    // [70][64] = 4480
#define QV_OFF    3160728    // [1024][64] = 65536
#define INVQ_OFF  3226264    // [1024][100] = 102400
#define SIM32_OFF 3328664    // [32][1024][70] = 2293760
#define PW_OFF    5694104    // [1024][70] = 71680
#define PQ4_OFF   5765784    // [4][1024][5][64] = 1310720
#define CLS_OFF   7404184    // [1024]
#define ALN_OFF   7405208    // [1024]
#define PSUMP_OFF 7406232    // [70][25][64] = 112000
#define SSQP_OFF  7518232    // [70][25] pad

#define PQ_ELEMS (NQ*NWAY*64)
#define SIM_STRIDE (NQ*NPAIR)

__device__ __forceinline__ float redsum64(float x){
  #pragma unroll
  for (int o = 1; o < 64; o <<= 1) x += __shfl_xor(x, o, 64);
  return x;
}

// ---------------- kN: per-sample L2(pos) normalize; support -> vptS, query -> invq+qv ----------------
// grid 1374: s < 350 support sample; else query q = s-350
__global__ __launch_bounds__(256) void kN(const float* __restrict__ feat,
                                          float* __restrict__ vptS,
                                          float* __restrict__ invq,
                                          float* __restrict__ qv){
  __shared__ float lds[64*101];
  __shared__ float inv[100];
  int s = blockIdx.x, t = threadIdx.x;
  const float* fp = feat + (size_t)s * 6400;
  #pragma unroll
  for (int i = 0; i < 25; i++){
    int j = t + 256*i;
    int d = j / 100, p = j - d*100;
    lds[d*101 + p] = fp[j];
  }
  __syncthreads();
  if (t < 100){
    float ss = 0.f;
    #pragma unroll
    for (int d = 0; d < 64; d++){ float x = lds[d*101 + t]; ss += x*x; }
    inv[t] = 1.f / fmaxf(sqrtf(ss), 1e-12f);
  }
  __syncthreads();
  if (s < NS){
    #pragma unroll
    for (int i = 0; i < 25; i++){
      int j = t + 256*i;
      int p = j >> 6, d = j & 63;
      vptS[(size_t)s*6400 + j] = lds[d*101 + p] * inv[p];
    }
  } else {
    int q = s - NS;
    if (t < 100) invq[q*100 + t] = inv[t];
    if (t < 64){
      float sum = 0.f;
      for (int p = 0; p < PP; p++) sum += lds[t*101 + p] * inv[p];
      qv[q*64 + t] = sum * 0.01f;
    }
  }
}

// ---------------- kVb: sum 5 shots -> vpt + B2 + MM + psumP + ssqP ----------------
// grid 1750: pair = b/25, chunk jc = b%25 (4 p's x 64 d)
__global__ __launch_bounds__(256) void kVb(const float* __restrict__ vptS,
                                           float* __restrict__ vpt,
                                           float* __restrict__ B2,
                                           float* __restrict__ MM,
                                           float* __restrict__ psumP,
                                           float* __restrict__ ssqP){
  __shared__ float l2[256];
  __shared__ float wssq[4];
  int b = blockIdx.x;
  int pair = b / 25, jc = b - pair*25;
  int n = pair / PRJ, v = pair - n*PRJ;
  int j0 = jc * 256;
  int t = threadIdx.x;
  int j = j0 + t;
  float s = 0.f;
  #pragma unroll
  for (int k = 0; k < KSHOT; k++){
    int sk = (n*KSHOT + k)*PRJ + v;
    s += vptS[(size_t)sk*6400 + j];
  }
  float val = s * 0.2f;
  vpt[(size_t)pair*6400 + j] = val;
  int p = j >> 6, d = j & 63;
  int plocal = p & 3;
  l2[d*4 + plocal] = val;
  float sq = redsum64(val*val);
  if ((t & 63) == 0) wssq[t >> 6] = sq;
  __syncthreads();
  if (t < 64){
    int p0 = j0 >> 6;
    float4 w4 = make_float4(l2[t*4+0], l2[t*4+1], l2[t*4+2], l2[t*4+3]);
    B2[(size_t)(t*100 + p0 + 0)*72 + pair] = w4.x;
    B2[(size_t)(t*100 + p0 + 1)*72 + pair] = w4.y;
    B2[(size_t)(t*100 + p0 + 2)*72 + pair] = w4.z;
    B2[(size_t)(t*100 + p0 + 3)*72 + pair] = w4.w;
    psumP[((size_t)pair*25 + jc)*64 + t] = w4.x + w4.y + w4.z + w4.w;
  }
  if (t >= 128 && t < 132){
    int i = t - 128;
    float m = 0.f;
    #pragma unroll
    for (int dd2 = 0; dd2 < 64; dd2++) m += l2[dd2*4 + i];
    MM[pair*100 + (j0 >> 6) + i] = m * (1.f/64.f);
  }
  if (t == 192)
    ssqP[pair*25 + jc] = wssq[0] + wssq[1] + wssq[2] + wssq[3];
}

// ---------------- kVc2: reduce chunk partials -> psum + vninv ----------------
__global__ __launch_bounds__(64) void kVc2(const float* __restrict__ psumP,
                                           const float* __restrict__ ssqP,
                                           float* __restrict__ psum,
                                           float* __restrict__ vninv){
  int pair = blockIdx.x, l = threadIdx.x;
  float s = 0.f;
  #pragma unroll
  for (int c = 0; c < 25; c++) s += psumP[((size_t)pair*25 + c)*64 + l];
  psum[pair*64 + l] = s;
  float sq = (l < 25) ? ssqP[pair*25 + l] : 0.f;
  float tot = redsum64(sq);
  if (l == 0) vninv[pair] = 1.f / fmaxf(sqrtf(tot), 1e-12f);
}

// ---------------- kS: lane=query, scalar-B FMA, f-split 32 ----------------
__global__ __launch_bounds__(256) void kS(const float* __restrict__ feat,
                                          const float* __restrict__ invq,
                                          const float* __restrict__ B2,
                                          float* __restrict__ sim32){
  __shared__ float A[100*66];
  int b = blockIdx.x;
  int qg = b & 15, fg = b >> 4;
  int q0 = qg * 64;
  int t = threadIdx.x;
  int l = t & 63;
  int wu = __builtin_amdgcn_readfirstlane(t >> 6);
  int pr0 = wu * 18;

  float acc[18];
  #pragma unroll
  for (int j = 0; j < 18; j++) acc[j] = 0.f;

  for (int cc = 0; cc < SUBCH; cc++){
    int fbase = (fg*SUBCH + cc) * 100;
    __syncthreads();
    for (int i = t; i < 1600; i += 256){
      int q = i / 25, r4 = i - q*25;
      float4 f4 = *(const float4*)(feat + (size_t)(NS + q0 + q)*6400 + fbase + r4*4);
      float4 v4 = *(const float4*)(invq + (q0 + q)*100 + r4*4);
      A[(r4*4+0)*66 + q] = f4.x * v4.x;
      A[(r4*4+1)*66 + q] = f4.y * v4.y;
      A[(r4*4+2)*66 + q] = f4.z * v4.z;
      A[(r4*4+3)*66 + q] = f4.w * v4.w;
    }
    __syncthreads();
    const float* Bb = B2 + (size_t)fbase*72 + pr0;   // wave-uniform -> s_load
    for (int r = 0; r < 100; r++){
      float a = A[r*66 + l];
      #pragma unroll
      for (int j = 0; j < 18; j++)
        acc[j] += a * Bb[r*72 + j];
    }
  }
  int qq = q0 + l;
  #pragma unroll
  for (int j = 0; j < 18; j++){
    int pr = pr0 + j;
    if (pr < NPAIR) sim32[(size_t)fg*SIM_STRIDE + qq*NPAIR + pr] = acc[j];
  }
}

// ---------------- kM: sum 32 f-chunk partials + per-(q,n) softmax over 14 views ----------------
__global__ __launch_bounds__(256) void kM(const float* __restrict__ sim32,
                                          const float* __restrict__ vninv,
                                          const float* __restrict__ temp,
                                          float* __restrict__ pw){
  int t = blockIdx.x*256 + threadIdx.x;
  if (t >= NQ*NWAY) return;
  int q = t / NWAY, n = t - q*NWAY;
  float invT = 1.f / (temp[0] + 1e-6f);
  float s[PRJ];
  #pragma unroll
  for (int v = 0; v < PRJ; v++) s[v] = 0.f;
  for (int c = 0; c < FGROUPS; c++){
    const float* sp = sim32 + (size_t)c*SIM_STRIDE + q*NPAIR + n*PRJ;
    #pragma unroll
    for (int v = 0; v < PRJ; v++) s[v] += sp[v];
  }
  float m = -3.4e38f;
  #pragma unroll
  for (int v = 0; v < PRJ; v++){
    s[v] = s[v] * vninv[n*PRJ + v] * invT;
    m = fmaxf(m, s[v]);
  }
  float sum = 0.f;
  #pragma unroll
  for (int v = 0; v < PRJ; v++){ s[v] = expf(s[v] - m); sum += s[v]; }
  float rs = 1.f / sum;
  #pragma unroll
  for (int v = 0; v < PRJ; v++) pw[q*NPAIR + n*PRJ + v] = s[v] * rs;
}

// ---------------- kP: p-split 4x, sg computed inline, partial outputs ----------------
__global__ __launch_bounds__(256) void kP(const float* __restrict__ vpt,
                                          const float* __restrict__ pw,
                                          const float* __restrict__ MM,
                                          float* __restrict__ pq4){
  __shared__ float sgl[16][PCHUNK];
  int b = blockIdx.x;
  int n  = b / 256;
  int r  = b - n*256;
  int qb = r >> 2;
  int s  = r & 3;
  int p0 = s * PCHUNK;
  int t = threadIdx.x, w = t >> 6, l = t & 63;
  int q0 = qb*16 + w*4;

  float wq[4][PRJ];
  #pragma unroll
  for (int j = 0; j < 4; j++)
    #pragma unroll
    for (int v = 0; v < PRJ; v++)
      wq[j][v] = pw[(q0+j)*NPAIR + n*PRJ + v];

  if (l < PCHUNK){
    #pragma unroll
    for (int j = 0; j < 4; j++){
      float ssg = 0.f;
      #pragma unroll
      for (int v = 0; v < PRJ; v++)
        ssg += wq[j][v] * MM[(n*PRJ + v)*100 + p0 + l];
      sgl[w*4 + j][l] = 1.f / (1.f + expf(-ssg));
    }
  }
  __syncthreads();

  float acc[4] = {0.f, 0.f, 0.f, 0.f};
  const float* vb = vpt + (size_t)n * PRJ * 6400;
  for (int pl = 0; pl < PCHUNK; pl++){
    int p = p0 + pl;
    float vv[PRJ];
    #pragma unroll
    for (int v = 0; v < PRJ; v++) vv[v] = vb[v*6400 + p*64 + l];
    #pragma unroll
    for (int j = 0; j < 4; j++){
      float dot = 0.f;
      #pragma unroll
      for (int v = 0; v < PRJ; v++) dot += wq[j][v] * vv[v];
      acc[j] += sgl[w*4 + j][pl] * dot;
    }
  }
  #pragma unroll
  for (int j = 0; j < 4; j++)
    pq4[(size_t)s*PQ_ELEMS + ((q0+j)*NWAY + n)*64 + l] = acc[j];
}

// ---------------- kF: 5 waves per query, wave = n; pq4-sum and base fused in ----------------
__global__ __launch_bounds__(320) void kF(const float* __restrict__ qv,
                                          const float* __restrict__ pq4,
                                          const float* __restrict__ psum,
                                          const float* __restrict__ Wq,
                                          const float* __restrict__ bq,
                                          const float* __restrict__ Wk,
                                          const float* __restrict__ bk,
                                          const float* __restrict__ gate,
                                          const int*   __restrict__ label,
                                          float* __restrict__ pred,
                                          float* __restrict__ cls,
                                          float* __restrict__ aln){
  __shared__ float qvl[64];
  __shared__ float qp[16];
  __shared__ float scn[NWAY], cosn[NWAY], c2n[NWAY];
  __shared__ float dl5[NWAY][64];
  int q = blockIdx.x, t = threadIdx.x;
  int w = t >> 6, l = t & 63;      // w = n

  float qvv = qv[q*64 + l];
  float qss = redsum64(qvv*qvv);
  float qn8 = fmaxf(sqrtf(qss), 1e-8f);
  if (w == 0) qvl[l] = qvv;
  __syncthreads();
  if (w == 0 && l < 16){
    float s = bq[l];
    #pragma unroll
    for (int d = 0; d < 64; d++) s += qvl[d] * Wq[d*16 + l];
    qp[l] = s;
  }
  __syncthreads();

  float wkq = 0.f;
  #pragma unroll
  for (int e = 0; e < 16; e++) wkq += Wk[l*16 + e] * qp[e];
  float qpb = 0.f;
  #pragma unroll
  for (int e = 0; e < 16; e++) qpb += qp[e] * bk[e];

  // fused kPr: sum 4 p-split partials (same order as old kPr)
  size_t idx = (size_t)(q*NWAY + w)*64 + l;
  float x = pq4[idx] + pq4[PQ_ELEMS + idx] + pq4[2*PQ_ELEMS + idx] + pq4[3*PQ_ELEMS + idx];

  float dq = redsum64(qvv * x);
  float ps = redsum64(x * x);
  float cosw = dq / (qn8 * fmaxf(sqrtf(ps), 1e-8f));
  float sd = redsum64(x * wkq);
  float scw = (sd + qpb) * 0.25f;
  if (l == 0){ scn[w] = scw; cosn[w] = cosw; }
  __syncthreads();

  float am = scn[0];
  #pragma unroll
  for (int n = 1; n < NWAY; n++) am = fmaxf(am, scn[n]);
  float asum = 0.f;
  #pragma unroll
  for (int n = 0; n < NWAY; n++) asum += expf(scn[n] - am);
  float attw = expf(scw - am) / asum;

  float g0 = gate[0], g1 = gate[1], g2 = gate[2];
  float gm = fmaxf(fmaxf(g0, g1), g2);
  float e0 = expf(g0 - gm), e1 = expf(g1 - gm), e2 = expf(g2 - gm);
  float gs = 1.f / (e0 + e1 + e2);
  float b0 = (e0 + e1 + e2) * gs;
  float b1 = (e1 + e2) * gs;
  float b2 = e2 * gs;

  // fused kB: base for this wave's (n=w, d=l), same order as old kB
  float bs = 0.f;
  #pragma unroll
  for (int v = 0; v < PRJ; v++) bs += psum[(w*PRJ + v)*64 + l];
  bs *= (1.f/1400.f);

  float f  = x * attw;
  float dd = fabsf(f - bs);
  dl5[w][l] = dd;
  int rank = 0;
  #pragma unroll 8
  for (int j = 0; j < 64; j++){
    float dj = dl5[w][j];
    rank += (dj > dd) || (dj == dd && j < l);
  }
  float cw = (rank < 16) ? b0 : (rank < 32) ? b1 : (rank < 48) ? b2 : 0.f;
  float gl = f * cw;
  float gss = redsum64(gl * gl);
  float num = redsum64(qvv * gl);
  float c2w = num / (qn8 * fmaxf(sqrtf(gss), 1e-12f));
  if (l == 0) c2n[w] = c2w;
  __syncthreads();

  float mx = c2n[0];
  #pragma unroll
  for (int n = 1; n < NWAY; n++) mx = fmaxf(mx, c2n[n]);
  float psum2 = 0.f;
  #pragma unroll
  for (int n = 0; n < NWAY; n++) psum2 += expf(c2n[n] - mx);
  if (l == 0) pred[q*NWAY + w] = expf(c2w - mx) / psum2;

  if (t == 0){
    int lab = label[q];
    float lm = LAMDA * mx;
    float lsum = 0.f;
    #pragma unroll
    for (int n = 0; n < NWAY; n++) lsum += expf(LAMDA * c2n[n] - lm);
    float c2l = c2n[lab], cosl = cosn[lab];
    float clsv = (lm + logf(lsum)) - LAMDA * c2l;
    float sum5 = 0.f, minn = 3.4e38f;
    #pragma unroll
    for (int n = 0; n < NWAY; n++){
      sum5 += cosn[n];
      if (n != lab) minn = fminf(minn, cosn[n]);
    }
    float hn = (sum5 - cosl - minn) * (1.f/3.f);
    float al = fmaxf(hn - cosl + MARGIN, 0.f);
    cls[q] = clsv; aln[q] = al;
  }
}

// ---------------- kL: loss reduction ----------------
__global__ __launch_bounds__(256) void kL(const float* __restrict__ cls,
                                          const float* __restrict__ aln,
                                          float* __restrict__ out){
  __shared__ float r1[256], r2[256];
  int t = threadIdx.x;
  float s1 = 0.f, s2 = 0.f;
  for (int i = t; i < NQ; i += 256){ s1 += cls[i]; s2 += aln[i]; }
  r1[t] = s1; r2[t] = s2;
  __syncthreads();
  for (int o = 128; o > 0; o >>= 1){
    if (t < o){ r1[t] += r1[t + o]; r2[t] += r2[t + o]; }
    __syncthreads();
  }
  if (t == 0)
    out[NQ*NWAY] = r1[0]*(1.f/NQ) + 0.3f*(r2[0]*(1.f/NQ));
}

extern "C" void kernel_launch(void* const* d_in, const int* in_sizes, int n_in,
                              void* d_out, int out_size, void* d_ws, size_t ws_size,
                              hipStream_t stream){
  const float* feat = (const float*)d_in[0];
  const float* temp = (const float*)d_in[1];
  const float* gate = (const float*)d_in[2];
  const float* Wq   = (const float*)d_in[3];
  const float* bq   = (const float*)d_in[4];
  const float* Wk   = (const float*)d_in[5];
  const float* bk   = (const float*)d_in[6];
  const int*   lab  = (const int*)d_in[7];
  float* out = (float*)d_out;
  float* ws  = (float*)d_ws;

  float* vpt   = ws + VPT_OFF;
  float* vptS  = ws + VPTS_OFF;
  float* B2    = ws + B2_OFF;
  float* MMp   = ws + MM_OFF;
  float* vninv = ws + VNINV_OFF;
  float* psum  = ws + PSUM_OFF;
  float* qv    = ws + QV_OFF;
  float* invq  = ws + INVQ_OFF;
  float* sim32 = ws + SIM32_OFF;
  float* pw    = ws + PW_OFF;
  float* pq4   = ws + PQ4_OFF;
  float* cls   = ws + CLS_OFF;
  float* aln   = ws + ALN_OFF;
  float* psumP = ws + PSUMP_OFF;
  float* ssqP  = ws + SSQP_OFF;

  hipLaunchKernelGGL(kN, dim3(NS + NQ), dim3(256), 0, stream, feat, vptS, invq, qv);
  hipLaunchKernelGGL(kVb, dim3(NPAIR*25), dim3(256), 0, stream, vptS, vpt, B2, MMp, psumP, ssqP);
  hipLaunchKernelGGL(kVc2, dim3(NPAIR), dim3(64), 0, stream, psumP, ssqP, psum, vninv);
  hipLaunchKernelGGL(kS, dim3(16*FGROUPS), dim3(256), 0, stream, feat, invq, B2, sim32);
  hipLaunchKernelGGL(kM, dim3((NQ*NWAY + 255)/256), dim3(256), 0, stream, sim32, vninv, temp, pw);
  hipLaunchKernelGGL(kP, dim3(NWAY*256), dim3(256), 0, stream, vpt, pw, MMp, pq4);
  hipLaunchKernelGGL(kF, dim3(NQ), dim3(320), 0, stream, qv, pq4, psum, Wq, bq, Wk, bk, gate, lab, out, cls, aln);
  hipLaunchKernelGGL(kL, dim3(1), dim3(256), 0, stream, cls, aln, out);
}